// Round 1
// baseline (2288.875 us; speedup 1.0000x reference)
//
#include <hip/hip_runtime.h>
#include <math.h>

#define B_    2048
#define V_    4096
#define L_    10
#define H_    512
#define E_    256
#define META_ 15
#define H4_   2048
#define TAU_  1.2f
#define EOS_  0
#define INIT_LEN_ (L_ + 1)

// ---- output layout (flat float32, in reference return order) ----
constexpr size_t OUT_SL  = (size_t)B_ * (L_ + 1) * V_;   // 92274688: seq_lengths [B]
constexpr size_t OUT_ENT = OUT_SL + B_;                  // entropy scalar
constexpr size_t OUT_EMB = OUT_ENT + 1;                  // embeds [B,L,E]
constexpr size_t OUT_SP  = OUT_EMB + (size_t)B_ * L_ * E_; // sentence_probability [B,V]

// ---- workspace layout (floats) ----
// E2G [V,4H] | WoutT [V,H] | h [B,H] | c [B,H] | gates [B,4H] | logits [B,V] | tok[B] | sl[B] | ents[B]
constexpr size_t WS_E2G    = 0;
constexpr size_t WS_WOUTT  = WS_E2G   + (size_t)V_ * H4_;   // 8388608
constexpr size_t WS_H      = WS_WOUTT + (size_t)V_ * H_;    // +2097152
constexpr size_t WS_C      = WS_H     + (size_t)B_ * H_;
constexpr size_t WS_GATES  = WS_C     + (size_t)B_ * H_;
constexpr size_t WS_LOGITS = WS_GATES + (size_t)B_ * H4_;
constexpr size_t WS_TOK    = WS_LOGITS+ (size_t)B_ * V_;    // ints
constexpr size_t WS_SL     = WS_TOK   + B_;
constexpr size_t WS_ENTS   = WS_SL    + B_;

// ---------------------------------------------------------------------------
// NT GEMM: C[M,N] = A[M,K] (row-major) * Bm[N,K]^T (row-major) + epilogue
// BM=BN=128, BK=8, 256 threads, 8x8 per thread.
// EPI 0: + bias0[col] + bias1[col]        (E2G build)
// EPI 1: + e2g[tokidx[row]*4H + col]      (gates)
// EPI 2: + bias0[col]                     (logits)
// ---------------------------------------------------------------------------
template <int EPI>
__global__ __launch_bounds__(256)
void gemm_nt(const float* __restrict__ A, const float* __restrict__ Bm,
             float* __restrict__ C, int M, int N, int K,
             const float* __restrict__ bias0, const float* __restrict__ bias1,
             const int* __restrict__ tokidx, const float* __restrict__ e2g)
{
    __shared__ float As[8][132];
    __shared__ float Bs[8][132];
    const int tid  = threadIdx.x;
    const int col0 = blockIdx.x * 128;
    const int row0 = blockIdx.y * 128;
    const int tx = tid & 15;          // 16 thread cols
    const int ty = tid >> 4;          // 16 thread rows
    const int lrow = tid >> 1;        // 0..127  (global-load row within tile)
    const int lkq  = (tid & 1) * 4;   // 0 or 4  (k quad)

    const float* Aptr = A + (size_t)(row0 + lrow) * K + lkq;
    const float* Bptr = Bm + (size_t)(col0 + lrow) * K + lkq;

    float acc[8][8] = {};

    for (int k0 = 0; k0 < K; k0 += 8) {
        float4 av = *(const float4*)(Aptr + k0);
        float4 bv = *(const float4*)(Bptr + k0);
        __syncthreads();   // protect LDS reuse from previous iteration's reads
        As[lkq + 0][lrow] = av.x; As[lkq + 1][lrow] = av.y;
        As[lkq + 2][lrow] = av.z; As[lkq + 3][lrow] = av.w;
        Bs[lkq + 0][lrow] = bv.x; Bs[lkq + 1][lrow] = bv.y;
        Bs[lkq + 2][lrow] = bv.z; Bs[lkq + 3][lrow] = bv.w;
        __syncthreads();
#pragma unroll
        for (int kk = 0; kk < 8; ++kk) {
            float4 a0 = *(const float4*)&As[kk][ty * 8];
            float4 a1 = *(const float4*)&As[kk][ty * 8 + 4];
            float4 b0 = *(const float4*)&Bs[kk][tx * 8];
            float4 b1 = *(const float4*)&Bs[kk][tx * 8 + 4];
            float ar[8] = {a0.x, a0.y, a0.z, a0.w, a1.x, a1.y, a1.z, a1.w};
            float br[8] = {b0.x, b0.y, b0.z, b0.w, b1.x, b1.y, b1.z, b1.w};
#pragma unroll
            for (int r = 0; r < 8; ++r)
#pragma unroll
                for (int cc = 0; cc < 8; ++cc)
                    acc[r][cc] = fmaf(ar[r], br[cc], acc[r][cc]);
        }
    }

    const int ccol = col0 + tx * 8;
#pragma unroll
    for (int r = 0; r < 8; ++r) {
        const int grow = row0 + ty * 8 + r;
        float* cp = C + (size_t)grow * N + ccol;
        const float* ep = nullptr;
        if (EPI == 1) ep = e2g + (size_t)tokidx[grow] * H4_ + ccol;
#pragma unroll
        for (int cc = 0; cc < 8; ++cc) {
            float v = acc[r][cc];
            if (EPI == 0) v += bias0[ccol + cc] + bias1[ccol + cc];
            if (EPI == 1) v += ep[cc];
            if (EPI == 2) v += bias0[ccol + cc];
            acc[r][cc] = v;
        }
        float4 s0 = make_float4(acc[r][0], acc[r][1], acc[r][2], acc[r][3]);
        float4 s1 = make_float4(acc[r][4], acc[r][5], acc[r][6], acc[r][7]);
        *(float4*)(cp)     = s0;
        *(float4*)(cp + 4) = s1;
    }
}

// ---------------------------------------------------------------------------
__global__ __launch_bounds__(256)
void transpose_wout(const float* __restrict__ W_out, float* __restrict__ WoutT)
{
    __shared__ float t[32][33];
    const int v0 = blockIdx.x * 32, k0 = blockIdx.y * 32;
    const int x = threadIdx.x & 31, y = threadIdx.x >> 5;   // 32 x 8
    for (int yy = y; yy < 32; yy += 8)
        t[yy][x] = W_out[(size_t)(k0 + yy) * V_ + v0 + x];
    __syncthreads();
    for (int yy = y; yy < 32; yy += 8)
        WoutT[(size_t)(v0 + yy) * H_ + k0 + x] = t[x][yy];
}

// h0 = hidden_state @ W_in + b_in ; c0 = 0
__global__ __launch_bounds__(256)
void h0_kernel(const float* __restrict__ hs, const float* __restrict__ W_in,
               const float* __restrict__ b_in, float* __restrict__ h,
               float* __restrict__ c)
{
    const int idx = blockIdx.x * 256 + threadIdx.x;   // B*H
    const int b = idx >> 9, j = idx & 511;
    float acc = b_in[j];
#pragma unroll
    for (int e = 0; e < META_; ++e)
        acc = fmaf(hs[b * META_ + e], W_in[e * H_ + j], acc);
    h[idx] = acc;
    c[idx] = 0.f;
}

// zero+one-hot the step-0 token rows, zero sentence_probability, init misc state
__global__ __launch_bounds__(256)
void init_outputs(float* __restrict__ out, int* __restrict__ tok,
                  int* __restrict__ sl, float* __restrict__ ents)
{
    const int tid = blockIdx.x * 256 + threadIdx.x;   // 2,097,152 threads
    // step-0 one-hot rows: out[b*11*V .. +V] = e_SOS
    {
        const int b = tid >> 10;          // V/4 = 1024 float4 per row
        const int q = tid & 1023;
        float4 z = make_float4(0.f, 0.f, 0.f, 0.f);
        if (q == 0) z.x = 1.0f;           // SOS = 0
        ((float4*)out)[(size_t)b * ((L_ + 1) * V_ / 4) + q] = z;
    }
    // sentence_probability zeros (odd offset -> scalar stores)
    for (size_t t = tid; t < (size_t)B_ * V_; t += (size_t)gridDim.x * 256)
        out[OUT_SP + t] = 0.f;
    if (tid < B_) { tok[tid] = 0; sl[tid] = INIT_LEN_; ents[tid] = 0.f; }
}

// LSTM pointwise + embeds output (uses incoming tok_idx)
__global__ __launch_bounds__(256)
void lstm_cell(const float* __restrict__ gates, float* __restrict__ h,
               float* __restrict__ c, const float* __restrict__ embedding,
               const int* __restrict__ tok, float* __restrict__ out, int step)
{
    const int idx = blockIdx.x * 256 + threadIdx.x;   // B*H
    const int b = idx >> 9, j = idx & 511;
    const size_t g0 = (size_t)b * H4_;
    const float ig = gates[g0 + j];
    const float fg = gates[g0 + H_ + j];
    const float gg = gates[g0 + 2 * H_ + j];
    const float og = gates[g0 + 3 * H_ + j];
    const float si = 1.f / (1.f + expf(-ig));
    const float sf = 1.f / (1.f + expf(-fg));
    const float so = 1.f / (1.f + expf(-og));
    const float cn = sf * c[idx] + si * tanhf(gg);
    c[idx] = cn;
    h[idx] = so * tanhf(cn);
    if (j < E_)
        out[OUT_EMB + ((size_t)b * L_ + step) * E_ + j] =
            embedding[(size_t)tok[b] * E_ + j];
}

// per-row: entropy (log-sum-exp), argmax(logits+gumbel), one-hot write, state update
__global__ __launch_bounds__(256)
void softmax_step(const float* __restrict__ logits, const float* __restrict__ gumbel,
                  float* __restrict__ out, int* __restrict__ tok,
                  int* __restrict__ sl, float* __restrict__ ents, int step)
{
    const int b   = blockIdx.x;
    const int tid = threadIdx.x;
    const float* lrow = logits + (size_t)b * V_;
    const float* grow = gumbel + ((size_t)step * B_ + b) * V_;
    __shared__ float lsm[V_];
    __shared__ float red_m[4], red_bv[4], red_s[4], red_t[4];
    __shared__ int   red_bi[4];
    __shared__ float s_M;
    __shared__ int   s_bi;

    float m = -3.4e38f, bv = -3.4e38f;
    int bi = 0x7fffffff;
    for (int q = tid; q < V_ / 4; q += 256) {
        float4 l4 = ((const float4*)lrow)[q];
        float4 g4 = ((const float4*)grow)[q];
        ((float4*)lsm)[q] = l4;
        m = fmaxf(m, fmaxf(fmaxf(l4.x, l4.y), fmaxf(l4.z, l4.w)));
        float p; const int i4 = q * 4;
        p = l4.x + g4.x; if (p > bv) { bv = p; bi = i4; }
        p = l4.y + g4.y; if (p > bv) { bv = p; bi = i4 + 1; }
        p = l4.z + g4.z; if (p > bv) { bv = p; bi = i4 + 2; }
        p = l4.w + g4.w; if (p > bv) { bv = p; bi = i4 + 3; }
    }
#pragma unroll
    for (int off = 32; off > 0; off >>= 1) {
        m = fmaxf(m, __shfl_down(m, off));
        float obv = __shfl_down(bv, off);
        int   obi = __shfl_down(bi, off);
        if (obv > bv || (obv == bv && obi < bi)) { bv = obv; bi = obi; }
    }
    const int wave = tid >> 6, lane = tid & 63;
    if (lane == 0) { red_m[wave] = m; red_bv[wave] = bv; red_bi[wave] = bi; }
    __syncthreads();
    if (tid == 0) {
        m = red_m[0]; bv = red_bv[0]; bi = red_bi[0];
        for (int w = 1; w < 4; ++w) {
            m = fmaxf(m, red_m[w]);
            if (red_bv[w] > bv || (red_bv[w] == bv && red_bi[w] < bi)) {
                bv = red_bv[w]; bi = red_bi[w];
            }
        }
        s_M = m; s_bi = bi;
    }
    __syncthreads();
    const float M = s_M;
    const int amax = s_bi;

    float s = 0.f, t = 0.f;
    for (int q = tid; q < V_; q += 256) {
        const float l = lsm[q];
        const float e = __expf(l - M);
        s += e; t += e * l;
    }
#pragma unroll
    for (int off = 32; off > 0; off >>= 1) {
        s += __shfl_down(s, off);
        t += __shfl_down(t, off);
    }
    if (lane == 0) { red_s[wave] = s; red_t[wave] = t; }

    // one-hot row write
    float* orow = out + ((size_t)b * (L_ + 1) + step + 1) * V_;
    const float4 z4 = make_float4(0.f, 0.f, 0.f, 0.f);
    for (int q = tid; q < V_ / 4; q += 256) ((float4*)orow)[q] = z4;
    __syncthreads();
    if (tid == 0) {
        const float ss = red_s[0] + red_s[1] + red_s[2] + red_s[3];
        const float tt = red_t[0] + red_t[1] + red_t[2] + red_t[3];
        const float ent = (M + logf(ss)) - tt / ss;
        ents[b] += ent;
        orow[amax] = 1.0f;
        tok[b] = amax;
        if (amax == EOS_ && sl[b] == INIT_LEN_) sl[b] = step + 2;
    }
}

__global__ __launch_bounds__(256)
void finalize(const int* __restrict__ sl, const float* __restrict__ ents,
              float* __restrict__ out)
{
    const int tid = threadIdx.x;
    float s = 0.f;
    for (int b = tid; b < B_; b += 256) {
        s += ents[b];
        out[OUT_SL + b] = (float)sl[b];
    }
    __shared__ float red[4];
#pragma unroll
    for (int off = 32; off > 0; off >>= 1) s += __shfl_down(s, off);
    if ((tid & 63) == 0) red[tid >> 6] = s;
    __syncthreads();
    if (tid == 0)
        out[OUT_ENT] = (red[0] + red[1] + red[2] + red[3]) / (float)B_ / (float)L_;
}

// ---------------------------------------------------------------------------
extern "C" void kernel_launch(void* const* d_in, const int* in_sizes, int n_in,
                              void* d_out, int out_size, void* d_ws, size_t ws_size,
                              hipStream_t stream)
{
    const float* hidden    = (const float*)d_in[0];
    const float* W_in      = (const float*)d_in[1];
    const float* b_in      = (const float*)d_in[2];
    const float* embedding = (const float*)d_in[3];
    const float* W_ih      = (const float*)d_in[4];
    const float* W_hh      = (const float*)d_in[5];
    const float* b_ih      = (const float*)d_in[6];
    const float* b_hh      = (const float*)d_in[7];
    const float* W_out     = (const float*)d_in[8];
    const float* b_out     = (const float*)d_in[9];
    const float* gumbel    = (const float*)d_in[10];
    float* out = (float*)d_out;

    float* ws   = (float*)d_ws;
    float* E2G   = ws + WS_E2G;
    float* WoutT = ws + WS_WOUTT;
    float* h     = ws + WS_H;
    float* c     = ws + WS_C;
    float* gates = ws + WS_GATES;
    float* logit = ws + WS_LOGITS;
    int*   tok   = (int*)(ws + WS_TOK);
    int*   sl    = (int*)(ws + WS_SL);
    float* ents  = ws + WS_ENTS;

    // one-time per call
    transpose_wout<<<dim3(V_ / 32, H_ / 32), 256, 0, stream>>>(W_out, WoutT);
    h0_kernel<<<(B_ * H_) / 256, 256, 0, stream>>>(hidden, W_in, b_in, h, c);
    init_outputs<<<(B_ * V_ / 4) / 256, 256, 0, stream>>>(out, tok, sl, ents);
    // E2G = embedding @ W_ih^T + b_ih + b_hh   [V, 4H]
    gemm_nt<0><<<dim3(H4_ / 128, V_ / 128), 256, 0, stream>>>(
        embedding, W_ih, E2G, V_, H4_, E_, b_ih, b_hh, nullptr, nullptr);

    for (int i = 0; i < L_; ++i) {
        // gates = h @ W_hh^T + E2G[tok]   [B, 4H]
        gemm_nt<1><<<dim3(H4_ / 128, B_ / 128), 256, 0, stream>>>(
            h, W_hh, gates, B_, H4_, H_, nullptr, nullptr, tok, E2G);
        lstm_cell<<<(B_ * H_) / 256, 256, 0, stream>>>(gates, h, c, embedding,
                                                       tok, out, i);
        // logits = h @ WoutT^T + b_out   [B, V]
        gemm_nt<2><<<dim3(V_ / 128, B_ / 128), 256, 0, stream>>>(
            h, WoutT, logit, B_, V_, H_, b_out, nullptr, nullptr, nullptr);
        softmax_step<<<B_, 256, 0, stream>>>(logit, gumbel, out, tok, sl, ents, i);
    }
    finalize<<<1, 256, 0, stream>>>(sl, ents, out);
}

// Round 2
// 988.451 us; speedup vs baseline: 2.3156x; 2.3156x over previous
//
#include <hip/hip_runtime.h>
#include <hip/hip_bf16.h>
#include <math.h>

typedef unsigned short u16;
typedef __attribute__((ext_vector_type(8))) short bf16x8;
typedef __attribute__((ext_vector_type(4))) float f32x4;

#define B_    2048
#define V_    4096
#define L_    10
#define H_    512
#define E_    256
#define META_ 15
#define H4_   2048
#define EOS_  0
#define INIT_LEN_ (L_ + 1)

// ---- output layout (flat float32, in reference return order) ----
constexpr size_t OUT_SL  = (size_t)B_ * (L_ + 1) * V_;     // seq_lengths [B]
constexpr size_t OUT_ENT = OUT_SL + B_;                    // entropy scalar
constexpr size_t OUT_EMB = OUT_ENT + 1;                    // embeds [B,L,E]
constexpr size_t OUT_SP  = OUT_EMB + (size_t)B_ * L_ * E_; // sentence_probability [B,V]

// ---- workspace layout ----
// f32:  E2G [V,4H] | BIG [B,V] (shared gates/logits) | c [B,H]
// u16:  woutT_hi/lo [V,H] | whh_hi/lo [4H,H] | h_hi/lo [B,H]
// int:  tok[B] sl[B] ; f32 ents[B]
constexpr size_t WS_E2G     = 0;
constexpr size_t WS_BIG     = WS_E2G + (size_t)V_ * H4_;
constexpr size_t WS_C       = WS_BIG + (size_t)B_ * V_;
constexpr size_t WS_F32_END = WS_C + (size_t)B_ * H_;
constexpr size_t U_WOUT_HI  = 0;
constexpr size_t U_WOUT_LO  = U_WOUT_HI + (size_t)V_ * H_;
constexpr size_t U_WHH_HI   = U_WOUT_LO + (size_t)V_ * H_;
constexpr size_t U_WHH_LO   = U_WHH_HI + (size_t)H4_ * H_;
constexpr size_t U_HHI      = U_WHH_LO + (size_t)H4_ * H_;
constexpr size_t U_HLO      = U_HHI + (size_t)B_ * H_;
constexpr size_t U_END      = U_HLO + (size_t)B_ * H_;

__device__ __forceinline__ u16 f2bf(float f) {
    union { __hip_bfloat16 b; u16 u; } cv; cv.b = __float2bfloat16(f); return cv.u;
}
__device__ __forceinline__ float bf2f(u16 u) {
    union { u16 u; __hip_bfloat16 b; } cv; cv.u = u; return __bfloat162float(cv.b);
}

__device__ __forceinline__ void gld16(const u16* g, void* l) {
    __builtin_amdgcn_global_load_lds(
        (const __attribute__((address_space(1))) unsigned int*)g,
        (__attribute__((address_space(3))) unsigned int*)l, 16, 0, 0);
}

// ---------------------------------------------------------------------------
// bf16x3 split MFMA NT GEMM: C[M,N] = A[M,K] * Bm[N,K]^T (+ epilogue)
// A = Ah+Al, B = Bh+Bl (bf16 hi/lo).  128x128 tile, BK=32, 4 waves 2x2.
// EPI 1: + e2g[tokidx[row]*4H + col]   (gates)
// EPI 2: + bias[col]                   (logits)
// ---------------------------------------------------------------------------
template <int EPI>
__global__ __launch_bounds__(256)
void gemm_mfma(const u16* __restrict__ Ah, const u16* __restrict__ Al,
               const u16* __restrict__ Bh, const u16* __restrict__ Bl,
               float* __restrict__ C, int N, int K,
               const float* __restrict__ bias, const int* __restrict__ tokidx,
               const float* __restrict__ e2g)
{
    __shared__ u16 As[2][128][32];   // [split][row][k]
    __shared__ u16 Bs[2][128][32];
    const int tid  = threadIdx.x;
    const int lane = tid & 63;
    const int wave = tid >> 6;
    const int wm = wave >> 1, wn = wave & 1;
    const int col0 = blockIdx.x * 128;
    const int row0 = blockIdx.y * 128;

    // staging: thread covers elements [tid*8, tid*8+8) of the 128x32 tile,
    // then +2048 (rows +64).  LDS dest = linear, wave-uniform base + lane*16.
    const int srow = tid >> 2;
    const int scol = (tid & 3) * 8;
    const size_t aoff = (size_t)(row0 + srow) * K + scol;
    const size_t boff = (size_t)(col0 + srow) * K + scol;
    const size_t skip = (size_t)64 * K;

    u16* lA0 = &As[0][0][0];
    u16* lA1 = &As[1][0][0];
    u16* lB0 = &Bs[0][0][0];
    u16* lB1 = &Bs[1][0][0];
    const int d0 = tid * 8;
    const int d1 = d0 + 2048;

    f32x4 acc[4][4] = {};
    const int fr = lane & 15;
    const int kq = lane >> 4;

    for (int k0 = 0; k0 < K; k0 += 32) {
        __syncthreads();                    // previous compute done
        gld16(Ah + aoff + k0,        lA0 + d0);
        gld16(Ah + aoff + k0 + skip, lA0 + d1);
        gld16(Al + aoff + k0,        lA1 + d0);
        gld16(Al + aoff + k0 + skip, lA1 + d1);
        gld16(Bh + boff + k0,        lB0 + d0);
        gld16(Bh + boff + k0 + skip, lB0 + d1);
        gld16(Bl + boff + k0,        lB1 + d0);
        gld16(Bl + boff + k0 + skip, lB1 + d1);
        __syncthreads();                    // compiler drains vmcnt before barrier

        bf16x8 ah[4], al[4], bh[4], bl[4];
#pragma unroll
        for (int i = 0; i < 4; ++i) {
            ah[i] = *(const bf16x8*)&As[0][wm * 64 + i * 16 + fr][kq * 8];
            al[i] = *(const bf16x8*)&As[1][wm * 64 + i * 16 + fr][kq * 8];
            bh[i] = *(const bf16x8*)&Bs[0][wn * 64 + i * 16 + fr][kq * 8];
            bl[i] = *(const bf16x8*)&Bs[1][wn * 64 + i * 16 + fr][kq * 8];
        }
#pragma unroll
        for (int mi = 0; mi < 4; ++mi)
#pragma unroll
            for (int ni = 0; ni < 4; ++ni) {
                acc[mi][ni] = __builtin_amdgcn_mfma_f32_16x16x32_bf16(ah[mi], bh[ni], acc[mi][ni], 0, 0, 0);
                acc[mi][ni] = __builtin_amdgcn_mfma_f32_16x16x32_bf16(ah[mi], bl[ni], acc[mi][ni], 0, 0, 0);
                acc[mi][ni] = __builtin_amdgcn_mfma_f32_16x16x32_bf16(al[mi], bh[ni], acc[mi][ni], 0, 0, 0);
            }
    }

    // C/D layout: col = lane&15, row = (lane>>4)*4 + reg
    const int ccol = col0 + wn * 64 + fr;
#pragma unroll
    for (int mi = 0; mi < 4; ++mi) {
#pragma unroll
        for (int r = 0; r < 4; ++r) {
            const int grow = row0 + wm * 64 + mi * 16 + kq * 4 + r;
            float* cp = C + (size_t)grow * N + ccol;
            const float* ep = (EPI == 1) ? (e2g + (size_t)tokidx[grow] * H4_ + ccol)
                                         : nullptr;
#pragma unroll
            for (int ni = 0; ni < 4; ++ni) {
                float v = acc[mi][ni][r];
                if (EPI == 1) v += ep[ni * 16];
                if (EPI == 2) v += bias[ccol + ni * 16];
                cp[ni * 16] = v;
            }
        }
    }
}

// ---------------------------------------------------------------------------
// exact-f32 NT GEMM (kept for the one-time E2G build)
// EPI 0: + bias0[col] + bias1[col]
// ---------------------------------------------------------------------------
template <int EPI>
__global__ __launch_bounds__(256)
void gemm_nt(const float* __restrict__ A, const float* __restrict__ Bm,
             float* __restrict__ C, int M, int N, int K,
             const float* __restrict__ bias0, const float* __restrict__ bias1)
{
    __shared__ float As[8][132];
    __shared__ float Bs[8][132];
    const int tid  = threadIdx.x;
    const int col0 = blockIdx.x * 128;
    const int row0 = blockIdx.y * 128;
    const int tx = tid & 15;
    const int ty = tid >> 4;
    const int lrow = tid >> 1;
    const int lkq  = (tid & 1) * 4;

    const float* Aptr = A + (size_t)(row0 + lrow) * K + lkq;
    const float* Bptr = Bm + (size_t)(col0 + lrow) * K + lkq;

    float acc[8][8] = {};

    for (int k0 = 0; k0 < K; k0 += 8) {
        float4 av = *(const float4*)(Aptr + k0);
        float4 bv = *(const float4*)(Bptr + k0);
        __syncthreads();
        As[lkq + 0][lrow] = av.x; As[lkq + 1][lrow] = av.y;
        As[lkq + 2][lrow] = av.z; As[lkq + 3][lrow] = av.w;
        Bs[lkq + 0][lrow] = bv.x; Bs[lkq + 1][lrow] = bv.y;
        Bs[lkq + 2][lrow] = bv.z; Bs[lkq + 3][lrow] = bv.w;
        __syncthreads();
#pragma unroll
        for (int kk = 0; kk < 8; ++kk) {
            float4 a0 = *(const float4*)&As[kk][ty * 8];
            float4 a1 = *(const float4*)&As[kk][ty * 8 + 4];
            float4 b0 = *(const float4*)&Bs[kk][tx * 8];
            float4 b1 = *(const float4*)&Bs[kk][tx * 8 + 4];
            float ar[8] = {a0.x, a0.y, a0.z, a0.w, a1.x, a1.y, a1.z, a1.w};
            float br[8] = {b0.x, b0.y, b0.z, b0.w, b1.x, b1.y, b1.z, b1.w};
#pragma unroll
            for (int r = 0; r < 8; ++r)
#pragma unroll
                for (int cc = 0; cc < 8; ++cc)
                    acc[r][cc] = fmaf(ar[r], br[cc], acc[r][cc]);
        }
    }

    const int ccol = col0 + tx * 8;
#pragma unroll
    for (int r = 0; r < 8; ++r) {
        const int grow = row0 + ty * 8 + r;
        float* cp = C + (size_t)grow * N + ccol;
#pragma unroll
        for (int cc = 0; cc < 8; ++cc) {
            float v = acc[r][cc];
            if (EPI == 0) v += bias0[ccol + cc] + bias1[ccol + cc];
            acc[r][cc] = v;
        }
        *(float4*)(cp)     = make_float4(acc[r][0], acc[r][1], acc[r][2], acc[r][3]);
        *(float4*)(cp + 4) = make_float4(acc[r][4], acc[r][5], acc[r][6], acc[r][7]);
    }
}

// ---------------------------------------------------------------------------
// W_out [H,V] -> transposed hi/lo bf16 splits [V,H]
__global__ __launch_bounds__(256)
void split_wout(const float* __restrict__ W_out, u16* __restrict__ hiT,
                u16* __restrict__ loT)
{
    __shared__ float t[32][33];
    const int v0 = blockIdx.x * 32, k0 = blockIdx.y * 32;
    const int x = threadIdx.x & 31, y = threadIdx.x >> 5;
    for (int yy = y; yy < 32; yy += 8)
        t[yy][x] = W_out[(size_t)(k0 + yy) * V_ + v0 + x];
    __syncthreads();
    for (int yy = y; yy < 32; yy += 8) {
        const float v = t[x][yy];
        const u16 h = f2bf(v);
        hiT[(size_t)(v0 + yy) * H_ + k0 + x] = h;
        loT[(size_t)(v0 + yy) * H_ + k0 + x] = f2bf(v - bf2f(h));
    }
}

// elementwise f32 -> bf16 hi/lo split (W_hh)
__global__ __launch_bounds__(256)
void split_mat(const float* __restrict__ X, u16* __restrict__ hi,
               u16* __restrict__ lo)
{
    const int i = blockIdx.x * 256 + threadIdx.x;   // one float4 per thread
    float4 v = ((const float4*)X)[i];
    const u16 h0 = f2bf(v.x), h1 = f2bf(v.y), h2 = f2bf(v.z), h3 = f2bf(v.w);
    ((ushort4*)hi)[i] = make_ushort4(h0, h1, h2, h3);
    ((ushort4*)lo)[i] = make_ushort4(f2bf(v.x - bf2f(h0)), f2bf(v.y - bf2f(h1)),
                                     f2bf(v.z - bf2f(h2)), f2bf(v.w - bf2f(h3)));
}

// h0 = hidden_state @ W_in + b_in (split to bf16 hi/lo); c0 = 0
__global__ __launch_bounds__(256)
void h0_kernel(const float* __restrict__ hs, const float* __restrict__ W_in,
               const float* __restrict__ b_in, u16* __restrict__ h_hi,
               u16* __restrict__ h_lo, float* __restrict__ c)
{
    const int idx = blockIdx.x * 256 + threadIdx.x;   // B*H
    const int b = idx >> 9, j = idx & 511;
    float acc = b_in[j];
#pragma unroll
    for (int e = 0; e < META_; ++e)
        acc = fmaf(hs[b * META_ + e], W_in[e * H_ + j], acc);
    const u16 hh = f2bf(acc);
    h_hi[idx] = hh;
    h_lo[idx] = f2bf(acc - bf2f(hh));
    c[idx] = 0.f;
}

__global__ __launch_bounds__(256)
void init_outputs(float* __restrict__ out, int* __restrict__ tok,
                  int* __restrict__ sl, float* __restrict__ ents)
{
    const int tid = blockIdx.x * 256 + threadIdx.x;
    {
        const int b = tid >> 10;
        const int q = tid & 1023;
        float4 z = make_float4(0.f, 0.f, 0.f, 0.f);
        if (q == 0) z.x = 1.0f;           // SOS = 0
        ((float4*)out)[(size_t)b * ((L_ + 1) * V_ / 4) + q] = z;
    }
    for (size_t t = tid; t < (size_t)B_ * V_; t += (size_t)gridDim.x * 256)
        out[OUT_SP + t] = 0.f;
    if (tid < B_) { tok[tid] = 0; sl[tid] = INIT_LEN_; ents[tid] = 0.f; }
}

// LSTM pointwise + embeds output; writes split h
__global__ __launch_bounds__(256)
void lstm_cell(const float* __restrict__ gates, u16* __restrict__ h_hi,
               u16* __restrict__ h_lo, float* __restrict__ c,
               const float* __restrict__ embedding, const int* __restrict__ tok,
               float* __restrict__ out, int step)
{
    const int idx = blockIdx.x * 256 + threadIdx.x;   // B*H
    const int b = idx >> 9, j = idx & 511;
    const size_t g0 = (size_t)b * H4_;
    const float ig = gates[g0 + j];
    const float fg = gates[g0 + H_ + j];
    const float gg = gates[g0 + 2 * H_ + j];
    const float og = gates[g0 + 3 * H_ + j];
    const float si = 1.f / (1.f + expf(-ig));
    const float sf = 1.f / (1.f + expf(-fg));
    const float so = 1.f / (1.f + expf(-og));
    const float cn = sf * c[idx] + si * tanhf(gg);
    c[idx] = cn;
    const float hv = so * tanhf(cn);
    const u16 hh = f2bf(hv);
    h_hi[idx] = hh;
    h_lo[idx] = f2bf(hv - bf2f(hh));
    if (j < E_)
        out[OUT_EMB + ((size_t)b * L_ + step) * E_ + j] =
            embedding[(size_t)tok[b] * E_ + j];
}

// per-row: entropy (LSE), argmax(logits+gumbel), one-hot write, state update
__global__ __launch_bounds__(256)
void softmax_step(const float* __restrict__ logits, const float* __restrict__ gumbel,
                  float* __restrict__ out, int* __restrict__ tok,
                  int* __restrict__ sl, float* __restrict__ ents, int step)
{
    const int b   = blockIdx.x;
    const int tid = threadIdx.x;
    const float* lrow = logits + (size_t)b * V_;
    const float* grow = gumbel + ((size_t)step * B_ + b) * V_;
    __shared__ float lsm[V_];
    __shared__ float red_m[4], red_bv[4], red_s[4], red_t[4];
    __shared__ int   red_bi[4];
    __shared__ float s_M;
    __shared__ int   s_bi;

    float m = -3.4e38f, bv = -3.4e38f;
    int bi = 0x7fffffff;
    for (int q = tid; q < V_ / 4; q += 256) {
        float4 l4 = ((const float4*)lrow)[q];
        float4 g4 = ((const float4*)grow)[q];
        ((float4*)lsm)[q] = l4;
        m = fmaxf(m, fmaxf(fmaxf(l4.x, l4.y), fmaxf(l4.z, l4.w)));
        float p; const int i4 = q * 4;
        p = l4.x + g4.x; if (p > bv) { bv = p; bi = i4; }
        p = l4.y + g4.y; if (p > bv) { bv = p; bi = i4 + 1; }
        p = l4.z + g4.z; if (p > bv) { bv = p; bi = i4 + 2; }
        p = l4.w + g4.w; if (p > bv) { bv = p; bi = i4 + 3; }
    }
#pragma unroll
    for (int off = 32; off > 0; off >>= 1) {
        m = fmaxf(m, __shfl_down(m, off));
        float obv = __shfl_down(bv, off);
        int   obi = __shfl_down(bi, off);
        if (obv > bv || (obv == bv && obi < bi)) { bv = obv; bi = obi; }
    }
    const int wave = tid >> 6, lane = tid & 63;
    if (lane == 0) { red_m[wave] = m; red_bv[wave] = bv; red_bi[wave] = bi; }
    __syncthreads();
    if (tid == 0) {
        m = red_m[0]; bv = red_bv[0]; bi = red_bi[0];
        for (int w = 1; w < 4; ++w) {
            m = fmaxf(m, red_m[w]);
            if (red_bv[w] > bv || (red_bv[w] == bv && red_bi[w] < bi)) {
                bv = red_bv[w]; bi = red_bi[w];
            }
        }
        s_M = m; s_bi = bi;
    }
    __syncthreads();
    const float M = s_M;
    const int amax = s_bi;

    float s = 0.f, t = 0.f;
    for (int q = tid; q < V_; q += 256) {
        const float l = lsm[q];
        const float e = __expf(l - M);
        s += e; t += e * l;
    }
#pragma unroll
    for (int off = 32; off > 0; off >>= 1) {
        s += __shfl_down(s, off);
        t += __shfl_down(t, off);
    }
    if (lane == 0) { red_s[wave] = s; red_t[wave] = t; }

    float* orow = out + ((size_t)b * (L_ + 1) + step + 1) * V_;
    const float4 z4 = make_float4(0.f, 0.f, 0.f, 0.f);
    for (int q = tid; q < V_ / 4; q += 256) ((float4*)orow)[q] = z4;
    __syncthreads();
    if (tid == 0) {
        const float ss = red_s[0] + red_s[1] + red_s[2] + red_s[3];
        const float tt = red_t[0] + red_t[1] + red_t[2] + red_t[3];
        const float ent = (M + logf(ss)) - tt / ss;
        ents[b] += ent;
        orow[amax] = 1.0f;
        tok[b] = amax;
        if (amax == EOS_ && sl[b] == INIT_LEN_) sl[b] = step + 2;
    }
}

__global__ __launch_bounds__(256)
void finalize(const int* __restrict__ sl, const float* __restrict__ ents,
              float* __restrict__ out)
{
    const int tid = threadIdx.x;
    float s = 0.f;
    for (int b = tid; b < B_; b += 256) {
        s += ents[b];
        out[OUT_SL + b] = (float)sl[b];
    }
    __shared__ float red[4];
#pragma unroll
    for (int off = 32; off > 0; off >>= 1) s += __shfl_down(s, off);
    if ((tid & 63) == 0) red[tid >> 6] = s;
    __syncthreads();
    if (tid == 0)
        out[OUT_ENT] = (red[0] + red[1] + red[2] + red[3]) / (float)B_ / (float)L_;
}

// ---------------------------------------------------------------------------
extern "C" void kernel_launch(void* const* d_in, const int* in_sizes, int n_in,
                              void* d_out, int out_size, void* d_ws, size_t ws_size,
                              hipStream_t stream)
{
    const float* hidden    = (const float*)d_in[0];
    const float* W_in      = (const float*)d_in[1];
    const float* b_in      = (const float*)d_in[2];
    const float* embedding = (const float*)d_in[3];
    const float* W_ih      = (const float*)d_in[4];
    const float* W_hh      = (const float*)d_in[5];
    const float* b_ih      = (const float*)d_in[6];
    const float* b_hh      = (const float*)d_in[7];
    const float* W_out     = (const float*)d_in[8];
    const float* b_out     = (const float*)d_in[9];
    const float* gumbel    = (const float*)d_in[10];
    float* out = (float*)d_out;

    float* ws    = (float*)d_ws;
    float* E2G   = ws + WS_E2G;
    float* big   = ws + WS_BIG;      // shared gates/logits
    float* c     = ws + WS_C;
    u16*   wsu   = (u16*)(ws + WS_F32_END);
    u16* wout_hi = wsu + U_WOUT_HI;
    u16* wout_lo = wsu + U_WOUT_LO;
    u16* whh_hi  = wsu + U_WHH_HI;
    u16* whh_lo  = wsu + U_WHH_LO;
    u16* h_hi    = wsu + U_HHI;
    u16* h_lo    = wsu + U_HLO;
    int* tok     = (int*)(wsu + U_END);
    int* sl      = tok + B_;
    float* ents  = (float*)(sl + B_);

    // one-time per call
    split_wout<<<dim3(V_ / 32, H_ / 32), 256, 0, stream>>>(W_out, wout_hi, wout_lo);
    split_mat<<<(H4_ * H_ / 4) / 256, 256, 0, stream>>>(W_hh, whh_hi, whh_lo);
    h0_kernel<<<(B_ * H_) / 256, 256, 0, stream>>>(hidden, W_in, b_in, h_hi, h_lo, c);
    init_outputs<<<(B_ * V_ / 4) / 256, 256, 0, stream>>>(out, tok, sl, ents);
    // E2G = embedding @ W_ih^T + b_ih + b_hh   [V, 4H]  (exact f32, once)
    gemm_nt<0><<<dim3(H4_ / 128, V_ / 128), 256, 0, stream>>>(
        embedding, W_ih, E2G, V_, H4_, E_, b_ih, b_hh);

    for (int i = 0; i < L_; ++i) {
        // gates = h @ W_hh^T + E2G[tok]   [B, 4H]
        gemm_mfma<1><<<dim3(H4_ / 128, B_ / 128), 256, 0, stream>>>(
            h_hi, h_lo, whh_hi, whh_lo, big, H4_, H_, nullptr, tok, E2G);
        lstm_cell<<<(B_ * H_) / 256, 256, 0, stream>>>(big, h_hi, h_lo, c,
                                                       embedding, tok, out, i);
        // logits = h @ WoutT^T + b_out   [B, V]
        gemm_mfma<2><<<dim3(V_ / 128, B_ / 128), 256, 0, stream>>>(
            h_hi, h_lo, wout_hi, wout_lo, big, V_, H_, b_out, nullptr, nullptr);
        softmax_step<<<B_, 256, 0, stream>>>(big, gumbel, out, tok, sl, ents, i);
    }
    finalize<<<1, 256, 0, stream>>>(sl, ents, out);
}

// Round 3
// 865.135 us; speedup vs baseline: 2.6457x; 1.1425x over previous
//
#include <hip/hip_runtime.h>
#include <hip/hip_bf16.h>
#include <math.h>

typedef unsigned short u16;
typedef __attribute__((ext_vector_type(8))) short bf16x8;
typedef __attribute__((ext_vector_type(4))) float f32x4;

#define B_    2048
#define V_    4096
#define L_    10
#define H_    512
#define E_    256
#define META_ 15
#define H4_   2048
#define W6_   (H4_ + V_)          // 6144 combined B rows (W_hh | WoutT)
#define EOS_  0
#define INIT_LEN_ (L_ + 1)

// ---- output layout (flat float32, reference return order) ----
constexpr size_t OUT_SL  = (size_t)B_ * (L_ + 1) * V_;
constexpr size_t OUT_ENT = OUT_SL + B_;
constexpr size_t OUT_EMB = OUT_ENT + 1;
constexpr size_t OUT_SP  = OUT_EMB + (size_t)B_ * L_ * E_;

// ---- workspace layout ----
// f32: E2G [V,4H] | LOGITS [B,V] | G [B,4H] | c [B,H]
// u16: w6_hi/lo [6144,512] | h_hi/lo [B,H]
// emb/wih bf16 splits overlay the LOGITS region (dead after E2G build).
constexpr size_t WS_E2G     = 0;
constexpr size_t WS_LOGITS  = WS_E2G    + (size_t)V_ * H4_;
constexpr size_t WS_G       = WS_LOGITS + (size_t)B_ * V_;
constexpr size_t WS_C       = WS_G      + (size_t)B_ * H4_;
constexpr size_t WS_F32_END = WS_C      + (size_t)B_ * H_;
constexpr size_t U_W6_HI    = 0;
constexpr size_t U_W6_LO    = U_W6_HI + (size_t)W6_ * H_;
constexpr size_t U_HHI      = U_W6_LO + (size_t)W6_ * H_;
constexpr size_t U_HLO      = U_HHI   + (size_t)B_ * H_;
constexpr size_t U_END      = U_HLO   + (size_t)B_ * H_;

__device__ __forceinline__ u16 f2bf(float f) {
    union { __hip_bfloat16 b; u16 u; } cv; cv.b = __float2bfloat16(f); return cv.u;
}
__device__ __forceinline__ float bf2f(u16 u) {
    union { u16 u; __hip_bfloat16 b; } cv; cv.u = u; return __bfloat162float(cv.b);
}

__device__ __forceinline__ void gld16(const u16* g, void* l) {
    __builtin_amdgcn_global_load_lds(
        (const __attribute__((address_space(1))) unsigned int*)g,
        (__attribute__((address_space(3))) unsigned int*)l, 16, 0, 0);
}

// ---------------------------------------------------------------------------
// bf16x3 split MFMA NT GEMM.  128x128 tile, BK=32, 4 waves 2x2.
// EPI 0: C0[row, col] (ldc=4H)  += bias0[col] + bias1[col]       (E2G build)
// EPI 1: merged: col<4H -> G (ldc=4H, raw); col>=4H -> LOGITS (ldc=V) + bias0
// Grid is XCD-chunk swizzled (column-clustered); nwg must be divisible by 8.
// ---------------------------------------------------------------------------
template <int EPI>
__global__ __launch_bounds__(256)
void gemm3(const u16* __restrict__ Ah, const u16* __restrict__ Al,
           const u16* __restrict__ Bh, const u16* __restrict__ Bl,
           float* __restrict__ C0, float* __restrict__ C1, int K,
           const float* __restrict__ bias0, const float* __restrict__ bias1,
           int xoff)
{
    __shared__ u16 As[2][128][32];
    __shared__ u16 Bs[2][128][32];
    const int tid  = threadIdx.x;
    const int lane = tid & 63;
    const int wave = tid >> 6;
    const int wm = wave >> 1, wn = wave & 1;

    // bijective XCD-chunked swizzle, column-clustered work order
    const int nwg  = gridDim.x * gridDim.y;
    const int bid  = blockIdx.y * gridDim.x + blockIdx.x;
    const int w    = (bid & 7) * (nwg >> 3) + (bid >> 3);
    const int colb = w / gridDim.y + xoff;
    const int rowb = w % gridDim.y;
    const int col0 = colb * 128;
    const int row0 = rowb * 128;

    const int srow = tid >> 2;
    const int scol = (tid & 3) * 8;
    const size_t aoff = (size_t)(row0 + srow) * K + scol;
    const size_t boff = (size_t)(col0 + srow) * K + scol;
    const size_t skip = (size_t)64 * K;

    u16* lA0 = &As[0][0][0];
    u16* lA1 = &As[1][0][0];
    u16* lB0 = &Bs[0][0][0];
    u16* lB1 = &Bs[1][0][0];
    const int d0 = tid * 8;
    const int d1 = d0 + 2048;

    f32x4 acc[4][4] = {};
    const int fr = lane & 15;
    const int kq = lane >> 4;

    for (int k0 = 0; k0 < K; k0 += 32) {
        __syncthreads();
        gld16(Ah + aoff + k0,        lA0 + d0);
        gld16(Ah + aoff + k0 + skip, lA0 + d1);
        gld16(Al + aoff + k0,        lA1 + d0);
        gld16(Al + aoff + k0 + skip, lA1 + d1);
        gld16(Bh + boff + k0,        lB0 + d0);
        gld16(Bh + boff + k0 + skip, lB0 + d1);
        gld16(Bl + boff + k0,        lB1 + d0);
        gld16(Bl + boff + k0 + skip, lB1 + d1);
        __syncthreads();

        bf16x8 ah[4], al[4], bh[4], bl[4];
#pragma unroll
        for (int i = 0; i < 4; ++i) {
            ah[i] = *(const bf16x8*)&As[0][wm * 64 + i * 16 + fr][kq * 8];
            al[i] = *(const bf16x8*)&As[1][wm * 64 + i * 16 + fr][kq * 8];
            bh[i] = *(const bf16x8*)&Bs[0][wn * 64 + i * 16 + fr][kq * 8];
            bl[i] = *(const bf16x8*)&Bs[1][wn * 64 + i * 16 + fr][kq * 8];
        }
#pragma unroll
        for (int mi = 0; mi < 4; ++mi)
#pragma unroll
            for (int ni = 0; ni < 4; ++ni) {
                acc[mi][ni] = __builtin_amdgcn_mfma_f32_16x16x32_bf16(ah[mi], bh[ni], acc[mi][ni], 0, 0, 0);
                acc[mi][ni] = __builtin_amdgcn_mfma_f32_16x16x32_bf16(ah[mi], bl[ni], acc[mi][ni], 0, 0, 0);
                acc[mi][ni] = __builtin_amdgcn_mfma_f32_16x16x32_bf16(al[mi], bh[ni], acc[mi][ni], 0, 0, 0);
            }
    }

    // C/D layout: col = lane&15, row = (lane>>4)*4 + reg
    const int cc0 = col0 + wn * 64 + fr;       // global B-row (= output col)
    float* Cbase;
    int ldc, ccol;
    bool addBias;
    if (EPI == 0) {
        Cbase = C0; ldc = H4_; ccol = cc0; addBias = true;
    } else {
        const bool isG = (col0 < H4_);
        Cbase = isG ? C0 : C1;
        ldc   = isG ? H4_ : V_;
        ccol  = isG ? cc0 : cc0 - H4_;
        addBias = !isG;
    }
#pragma unroll
    for (int mi = 0; mi < 4; ++mi) {
#pragma unroll
        for (int r = 0; r < 4; ++r) {
            const int grow = row0 + wm * 64 + mi * 16 + kq * 4 + r;
            float* cp = Cbase + (size_t)grow * ldc + ccol;
#pragma unroll
            for (int ni = 0; ni < 4; ++ni) {
                float v = acc[mi][ni][r];
                if (EPI == 0) v += bias0[ccol + ni * 16] + bias1[ccol + ni * 16];
                if (EPI == 1 && addBias) v += bias0[ccol + ni * 16];
                cp[ni * 16] = v;
            }
        }
    }
}

// ---------------------------------------------------------------------------
// W_out [H,V] -> transposed hi/lo bf16 splits appended at combined rows
__global__ __launch_bounds__(256)
void split_wout(const float* __restrict__ W_out, u16* __restrict__ hiT,
                u16* __restrict__ loT)
{
    __shared__ float t[32][33];
    const int v0 = blockIdx.x * 32, k0 = blockIdx.y * 32;
    const int x = threadIdx.x & 31, y = threadIdx.x >> 5;
    for (int yy = y; yy < 32; yy += 8)
        t[yy][x] = W_out[(size_t)(k0 + yy) * V_ + v0 + x];
    __syncthreads();
    for (int yy = y; yy < 32; yy += 8) {
        const float v = t[x][yy];
        const u16 h = f2bf(v);
        hiT[(size_t)(v0 + yy) * H_ + k0 + x] = h;
        loT[(size_t)(v0 + yy) * H_ + k0 + x] = f2bf(v - bf2f(h));
    }
}

// elementwise f32 -> bf16 hi/lo split
__global__ __launch_bounds__(256)
void split_mat(const float* __restrict__ X, u16* __restrict__ hi,
               u16* __restrict__ lo)
{
    const int i = blockIdx.x * 256 + threadIdx.x;
    float4 v = ((const float4*)X)[i];
    const u16 h0 = f2bf(v.x), h1 = f2bf(v.y), h2 = f2bf(v.z), h3 = f2bf(v.w);
    ((ushort4*)hi)[i] = make_ushort4(h0, h1, h2, h3);
    ((ushort4*)lo)[i] = make_ushort4(f2bf(v.x - bf2f(h0)), f2bf(v.y - bf2f(h1)),
                                     f2bf(v.z - bf2f(h2)), f2bf(v.w - bf2f(h3)));
}

// h0 = hidden_state @ W_in + b_in (split); c0 = 0
__global__ __launch_bounds__(256)
void h0_kernel(const float* __restrict__ hs, const float* __restrict__ W_in,
               const float* __restrict__ b_in, u16* __restrict__ h_hi,
               u16* __restrict__ h_lo, float* __restrict__ c)
{
    const int idx = blockIdx.x * 256 + threadIdx.x;
    const int b = idx >> 9, j = idx & 511;
    float acc = b_in[j];
#pragma unroll
    for (int e = 0; e < META_; ++e)
        acc = fmaf(hs[b * META_ + e], W_in[e * H_ + j], acc);
    const u16 hh = f2bf(acc);
    h_hi[idx] = hh;
    h_lo[idx] = f2bf(acc - bf2f(hh));
    c[idx] = 0.f;
}

__global__ __launch_bounds__(256)
void init_outputs(float* __restrict__ out, int* __restrict__ tok,
                  int* __restrict__ sl, float* __restrict__ ents)
{
    const int tid = blockIdx.x * 256 + threadIdx.x;
    {
        const int b = tid >> 10;
        const int q = tid & 1023;
        float4 z = make_float4(0.f, 0.f, 0.f, 0.f);
        if (q == 0) z.x = 1.0f;           // SOS = 0
        ((float4*)out)[(size_t)b * ((L_ + 1) * V_ / 4) + q] = z;
    }
    for (size_t t = tid; t < (size_t)B_ * V_; t += (size_t)gridDim.x * 256)
        out[OUT_SP + t] = 0.f;
    if (tid < B_) { tok[tid] = 0; sl[tid] = INIT_LEN_; ents[tid] = 0.f; }
}

// LSTM pointwise: gates = G + E2G[tok]; writes split h, embeds output
__global__ __launch_bounds__(256)
void lstm_cell(const float* __restrict__ G, const float* __restrict__ e2g,
               u16* __restrict__ h_hi, u16* __restrict__ h_lo,
               float* __restrict__ c, const float* __restrict__ embedding,
               const int* __restrict__ tok, float* __restrict__ out, int step)
{
    const int idx = blockIdx.x * 256 + threadIdx.x;   // B*H
    const int b = idx >> 9, j = idx & 511;
    const size_t g0 = (size_t)b * H4_;
    const size_t e0 = (size_t)tok[b] * H4_;
    const float ig = G[g0 + j]          + e2g[e0 + j];
    const float fg = G[g0 + H_ + j]     + e2g[e0 + H_ + j];
    const float gg = G[g0 + 2 * H_ + j] + e2g[e0 + 2 * H_ + j];
    const float og = G[g0 + 3 * H_ + j] + e2g[e0 + 3 * H_ + j];
    const float si = 1.f / (1.f + expf(-ig));
    const float sf = 1.f / (1.f + expf(-fg));
    const float so = 1.f / (1.f + expf(-og));
    const float cn = sf * c[idx] + si * tanhf(gg);
    c[idx] = cn;
    const float hv = so * tanhf(cn);
    const u16 hh = f2bf(hv);
    h_hi[idx] = hh;
    h_lo[idx] = f2bf(hv - bf2f(hh));
    if (j < E_)
        out[OUT_EMB + ((size_t)b * L_ + step) * E_ + j] =
            embedding[(size_t)tok[b] * E_ + j];
}

// per-row: entropy (LSE), argmax(logits+gumbel), one-hot write, state update
__global__ __launch_bounds__(256)
void softmax_step(const float* __restrict__ logits, const float* __restrict__ gumbel,
                  float* __restrict__ out, int* __restrict__ tok,
                  int* __restrict__ sl, float* __restrict__ ents, int step)
{
    const int b   = blockIdx.x;
    const int tid = threadIdx.x;
    const float* lrow = logits + (size_t)b * V_;
    const float* grow = gumbel + ((size_t)step * B_ + b) * V_;
    __shared__ float lsm[V_];
    __shared__ float red_m[4], red_bv[4], red_s[4], red_t[4];
    __shared__ int   red_bi[4];
    __shared__ float s_M;
    __shared__ int   s_bi;

    float m = -3.4e38f, bv = -3.4e38f;
    int bi = 0x7fffffff;
    for (int q = tid; q < V_ / 4; q += 256) {
        float4 l4 = ((const float4*)lrow)[q];
        float4 g4 = ((const float4*)grow)[q];
        ((float4*)lsm)[q] = l4;
        m = fmaxf(m, fmaxf(fmaxf(l4.x, l4.y), fmaxf(l4.z, l4.w)));
        float p; const int i4 = q * 4;
        p = l4.x + g4.x; if (p > bv) { bv = p; bi = i4; }
        p = l4.y + g4.y; if (p > bv) { bv = p; bi = i4 + 1; }
        p = l4.z + g4.z; if (p > bv) { bv = p; bi = i4 + 2; }
        p = l4.w + g4.w; if (p > bv) { bv = p; bi = i4 + 3; }
    }
#pragma unroll
    for (int off = 32; off > 0; off >>= 1) {
        m = fmaxf(m, __shfl_down(m, off));
        float obv = __shfl_down(bv, off);
        int   obi = __shfl_down(bi, off);
        if (obv > bv || (obv == bv && obi < bi)) { bv = obv; bi = obi; }
    }
    const int wave = tid >> 6, lane = tid & 63;
    if (lane == 0) { red_m[wave] = m; red_bv[wave] = bv; red_bi[wave] = bi; }
    __syncthreads();
    if (tid == 0) {
        m = red_m[0]; bv = red_bv[0]; bi = red_bi[0];
        for (int w = 1; w < 4; ++w) {
            m = fmaxf(m, red_m[w]);
            if (red_bv[w] > bv || (red_bv[w] == bv && red_bi[w] < bi)) {
                bv = red_bv[w]; bi = red_bi[w];
            }
        }
        s_M = m; s_bi = bi;
    }
    __syncthreads();
    const float M = s_M;
    const int amax = s_bi;

    float s = 0.f, t = 0.f;
    for (int q = tid; q < V_; q += 256) {
        const float l = lsm[q];
        const float e = __expf(l - M);
        s += e; t += e * l;
    }
#pragma unroll
    for (int off = 32; off > 0; off >>= 1) {
        s += __shfl_down(s, off);
        t += __shfl_down(t, off);
    }
    if (lane == 0) { red_s[wave] = s; red_t[wave] = t; }

    float* orow = out + ((size_t)b * (L_ + 1) + step + 1) * V_;
    const float4 z4 = make_float4(0.f, 0.f, 0.f, 0.f);
    for (int q = tid; q < V_ / 4; q += 256) ((float4*)orow)[q] = z4;
    __syncthreads();
    if (tid == 0) {
        const float ss = red_s[0] + red_s[1] + red_s[2] + red_s[3];
        const float tt = red_t[0] + red_t[1] + red_t[2] + red_t[3];
        const float ent = (M + logf(ss)) - tt / ss;
        ents[b] += ent;
        orow[amax] = 1.0f;
        tok[b] = amax;
        if (amax == EOS_ && sl[b] == INIT_LEN_) sl[b] = step + 2;
    }
}

__global__ __launch_bounds__(256)
void finalize(const int* __restrict__ sl, const float* __restrict__ ents,
              float* __restrict__ out)
{
    const int tid = threadIdx.x;
    float s = 0.f;
    for (int b = tid; b < B_; b += 256) {
        s += ents[b];
        out[OUT_SL + b] = (float)sl[b];
    }
    __shared__ float red[4];
#pragma unroll
    for (int off = 32; off > 0; off >>= 1) s += __shfl_down(s, off);
    if ((tid & 63) == 0) red[tid >> 6] = s;
    __syncthreads();
    if (tid == 0)
        out[OUT_ENT] = (red[0] + red[1] + red[2] + red[3]) / (float)B_ / (float)L_;
}

// ---------------------------------------------------------------------------
extern "C" void kernel_launch(void* const* d_in, const int* in_sizes, int n_in,
                              void* d_out, int out_size, void* d_ws, size_t ws_size,
                              hipStream_t stream)
{
    const float* hidden    = (const float*)d_in[0];
    const float* W_in      = (const float*)d_in[1];
    const float* b_in      = (const float*)d_in[2];
    const float* embedding = (const float*)d_in[3];
    const float* W_ih      = (const float*)d_in[4];
    const float* W_hh      = (const float*)d_in[5];
    const float* b_ih      = (const float*)d_in[6];
    const float* b_hh      = (const float*)d_in[7];
    const float* W_out     = (const float*)d_in[8];
    const float* b_out     = (const float*)d_in[9];
    const float* gumbel    = (const float*)d_in[10];
    float* out = (float*)d_out;

    float* ws    = (float*)d_ws;
    float* E2G   = ws + WS_E2G;
    float* logit = ws + WS_LOGITS;
    float* G     = ws + WS_G;
    float* c     = ws + WS_C;
    u16*   wsu   = (u16*)(ws + WS_F32_END);
    u16* w6_hi   = wsu + U_W6_HI;
    u16* w6_lo   = wsu + U_W6_LO;
    u16* h_hi    = wsu + U_HHI;
    u16* h_lo    = wsu + U_HLO;
    int* tok     = (int*)(wsu + U_END);
    int* sl      = tok + B_;
    float* ents  = (float*)(sl + B_);
    // emb/wih bf16 splits overlay the LOGITS region (dead after E2G build)
    u16* emb_hi  = (u16*)logit;
    u16* emb_lo  = emb_hi + (size_t)V_ * E_;
    u16* wih_hi  = emb_lo + (size_t)V_ * E_;
    u16* wih_lo  = wih_hi + (size_t)H4_ * E_;

    // ---- one-time per call ----
    split_mat<<<(H4_ * H_ / 4) / 256, 256, 0, stream>>>(W_hh, w6_hi, w6_lo);
    split_wout<<<dim3(V_ / 32, H_ / 32), 256, 0, stream>>>(
        W_out, w6_hi + (size_t)H4_ * H_, w6_lo + (size_t)H4_ * H_);
    split_mat<<<(V_ * E_ / 4) / 256, 256, 0, stream>>>(embedding, emb_hi, emb_lo);
    split_mat<<<(H4_ * E_ / 4) / 256, 256, 0, stream>>>(W_ih, wih_hi, wih_lo);
    h0_kernel<<<(B_ * H_) / 256, 256, 0, stream>>>(hidden, W_in, b_in, h_hi, h_lo, c);
    init_outputs<<<(B_ * V_ / 4) / 256, 256, 0, stream>>>(out, tok, sl, ents);
    // E2G = embedding @ W_ih^T + b_ih + b_hh   [V, 4H]   (MFMA bf16x3)
    gemm3<0><<<dim3(H4_ / 128, V_ / 128), 256, 0, stream>>>(
        emb_hi, emb_lo, wih_hi, wih_lo, E2G, nullptr, E_, b_ih, b_hh, 0);
    // G0 = h0 @ W_hh^T  (G-region columns only)
    gemm3<1><<<dim3(H4_ / 128, B_ / 128), 256, 0, stream>>>(
        h_hi, h_lo, w6_hi, w6_lo, G, logit, H_, b_out, nullptr, 0);

    for (int i = 0; i < L_; ++i) {
        lstm_cell<<<(B_ * H_) / 256, 256, 0, stream>>>(G, E2G, h_hi, h_lo, c,
                                                       embedding, tok, out, i);
        if (i < L_ - 1) {
            // [G_{i+1} | logits_i] = h_{i+1} @ [W_hh | WoutT]^T
            gemm3<1><<<dim3(W6_ / 128, B_ / 128), 256, 0, stream>>>(
                h_hi, h_lo, w6_hi, w6_lo, G, logit, H_, b_out, nullptr, 0);
        } else {
            // logits only
            gemm3<1><<<dim3(V_ / 128, B_ / 128), 256, 0, stream>>>(
                h_hi, h_lo, w6_hi, w6_lo, G, logit, H_, b_out, nullptr, H4_ / 128);
        }
        softmax_step<<<B_, 256, 0, stream>>>(logit, gumbel, out, tok, sl, ents, i);
    }
    finalize<<<1, 256, 0, stream>>>(sl, ents, out);
}